// Round 2
// baseline (334.366 us; speedup 1.0000x reference)
//
#include <hip/hip_runtime.h>

// db4 DWT, mode='symmetric', matching the JAX reference exactly:
//   ext[i] = x[reflect(i-6)],  reflect: g<0 -> -1-g ; g>=N -> 2N-1-g
//   cA[k] = sum_t ext[2k+t] * w[t]
//   cD[k] = sum_t ext[2k+t] * ((t&1) ? -w[7-t] : +w[7-t])
//   K = (N+7)/2 ; outputs: cA (B,K) || cD (B,K) || x3 (B,8) passthrough
//
// R2 design: register-window, no LDS, no barriers. Thread = 16 consecutive
// outputs; 10x global_load_dwordx4 window (high MLP), 256 fully-unrolled FMAs
// (32 independent chains), row-uniform float2/scalar store dispatch.
// Taps hardcoded (fixed constants in setup_inputs).

#define OUTS_PER_THREAD 16
#define TILE_K (256 * OUTS_PER_THREAD)   // 4096 outputs per block

__device__ __forceinline__ constexpr float WLc(int t) {
    constexpr float w[8] = {
        0.23037781330885523f,  0.7148465705525415f,  0.6308807679295904f,
       -0.02798376941698385f, -0.18703481171888114f, 0.030841381835986965f,
        0.032883011666982945f,-0.010597401784997278f };
    return w[t];
}
__device__ __forceinline__ constexpr float WHc(int t) {
    return (t & 1) ? -WLc(7 - t) : WLc(7 - t);
}

__global__ __launch_bounds__(256) void dwt_db4_kernel(
    const float* __restrict__ x, float* __restrict__ out,
    int B, int N, int K, int tiles_per_row)
{
    const int blk  = blockIdx.x;
    const int row  = blk / tiles_per_row;
    const int tile = blk - row * tiles_per_row;
    const int k0   = tile * TILE_K + threadIdx.x * OUTS_PER_THREAD;
    if (k0 >= K) return;

    const float* __restrict__ xr = x + (long long)row * N;
    const long long g0 = 2LL * k0 - 8;    // window base; multiple of 4 floats

    union { float4 v[10]; float f[40]; } win;

    if (g0 >= 0 && g0 + 40 <= (long long)N) {
        // interior thread (all but 2 per row): 10 coalesced 16B loads
        const float4* __restrict__ s = reinterpret_cast<const float4*>(xr + g0);
        #pragma unroll
        for (int v = 0; v < 10; ++v) win.v[v] = s[v];
    } else {
        // edge thread: scalar gather with symmetric reflection
        #pragma unroll
        for (int m = 0; m < 40; ++m) {
            long long g = g0 + m;
            if (g < 0) g = -1 - g;
            if (g >= (long long)N) g = 2LL * N - 1 - g;
            win.f[m] = xr[g];
        }
    }

    // output j uses window floats [2j+2 .. 2j+9]
    float a[OUTS_PER_THREAD], d[OUTS_PER_THREAD];
    #pragma unroll
    for (int j = 0; j < OUTS_PER_THREAD; ++j) {
        float va = win.f[2*j + 2] * WLc(0);
        float vd = win.f[2*j + 2] * WHc(0);
        #pragma unroll
        for (int t = 1; t < 8; ++t) {
            va = fmaf(win.f[2*j + 2 + t], WLc(t), va);
            vd = fmaf(win.f[2*j + 2 + t], WHc(t), vd);
        }
        a[j] = va; d[j] = vd;
    }

    const long long obase = (long long)row * K + k0;
    float* __restrict__ oA = out + obase;
    float* __restrict__ oD = out + obase + (long long)B * K;
    const int nvalid = K - k0;

    if (nvalid >= OUTS_PER_THREAD) {
        if ((obase & 1) == 0) {
            // 8B-aligned rows: float2 stores (row-uniform branch, no divergence)
            float2* pA = reinterpret_cast<float2*>(oA);
            float2* pD = reinterpret_cast<float2*>(oD);
            #pragma unroll
            for (int j = 0; j < OUTS_PER_THREAD/2; ++j) {
                pA[j] = make_float2(a[2*j], a[2*j+1]);
                pD[j] = make_float2(d[2*j], d[2*j+1]);
            }
        } else {
            #pragma unroll
            for (int j = 0; j < OUTS_PER_THREAD; ++j) { oA[j] = a[j]; oD[j] = d[j]; }
        }
    } else {
        for (int j = 0; j < nvalid; ++j) { oA[j] = a[j]; oD[j] = d[j]; }
    }
}

__global__ void copy_tail_kernel(const float* __restrict__ src,
                                 float* __restrict__ dst, int n)
{
    int i = blockIdx.x * blockDim.x + threadIdx.x;
    if (i < n) dst[i] = src[i];
}

extern "C" void kernel_launch(void* const* d_in, const int* in_sizes, int n_in,
                              void* d_out, int out_size, void* d_ws, size_t ws_size,
                              hipStream_t stream) {
    const float* x1 = (const float*)d_in[0];
    // d_in[1] = x2: unused by the reference
    const float* x3 = (const float*)d_in[2];
    float* out = (float*)d_out;

    const int B = in_sizes[2] / 8;        // 512
    const int N = in_sizes[0] / B;        // 65536
    const int K = (N + 7) / 2;            // 32771
    const int tiles = (K + TILE_K - 1) / TILE_K;   // 9

    dwt_db4_kernel<<<B * tiles, 256, 0, stream>>>(x1, out, B, N, K, tiles);

    const int n3 = in_sizes[2];           // 4096
    copy_tail_kernel<<<(n3 + 255) / 256, 256, 0, stream>>>(
        x3, out + 2LL * B * K, n3);
}

// Round 6
// 235.421 us; speedup vs baseline: 1.4203x; 1.4203x over previous
//
#include <hip/hip_runtime.h>

// db4 DWT, mode='symmetric', matching the JAX reference exactly:
//   cA[k] = sum_t x[reflect(2k+t-6)] * w[t]
//   cD[k] = sum_t x[reflect(2k+t-6)] * ((t&1) ? -w[7-t] : +w[7-t])
//   reflect: g<0 -> -1-g ; g>=N -> 2N-1-g ;  K = (N+7)/2
//   outputs: cA (B,K) || cD (B,K) || x3 (B,8) passthrough
//
// R3 design (3rd resubmit; broker timeouts, never benched):
// lane-contiguous, no LDS, no barriers. Thread t computes outputs
// {2t, 2t+1} from window x[4t-8 .. 4t+3] = 3 float4 loads at consecutive
// float4 indices across lanes (perfect coalescing; overlap served by L1/LLC).
// Stores are lane-contiguous float2 (even rows) or scalar (odd rows).

__device__ __forceinline__ constexpr float WLc(int t) {
    constexpr float w[8] = {
        0.23037781330885523f,  0.7148465705525415f,  0.6308807679295904f,
       -0.02798376941698385f, -0.18703481171888114f, 0.030841381835986965f,
        0.032883011666982945f,-0.010597401784997278f };
    return w[t];
}
__device__ __forceinline__ constexpr float WHc(int t) {
    return (t & 1) ? -WLc(7 - t) : WLc(7 - t);
}

__global__ __launch_bounds__(256) void dwt_db4_kernel(
    const float* __restrict__ x, float* __restrict__ out,
    int B, int N, int K, int tiles_per_row)
{
    const int blk  = blockIdx.x;
    const int row  = blk / tiles_per_row;
    const int tile = blk - row * tiles_per_row;
    const int trow = tile * 256 + threadIdx.x;   // thread index within the row
    const int k0   = 2 * trow;                   // first of this thread's 2 outputs
    if (k0 >= K) return;

    const float* __restrict__ xr = x + (long long)row * N;
    const int gbase = 4 * trow - 8;              // float index of f[0]; 16B-aligned

    float f[12];
    if (gbase >= 0 && gbase + 12 <= N) {
        // interior (all threads except 2 left-edge + 2 right-edge per row)
        const float4* __restrict__ s = reinterpret_cast<const float4*>(xr + gbase);
        float4 v0 = s[0], v1 = s[1], v2 = s[2];  // lane-consecutive float4s
        f[0]=v0.x; f[1]=v0.y; f[2]=v0.z; f[3]=v0.w;
        f[4]=v1.x; f[5]=v1.y; f[6]=v1.z; f[7]=v1.w;
        f[8]=v2.x; f[9]=v2.y; f[10]=v2.z; f[11]=v2.w;
    } else {
        #pragma unroll
        for (int m = 0; m < 12; ++m) {
            int g = gbase + m;
            if (g < 0) g = -1 - g;
            if (g >= N) g = 2 * N - 1 - g;
            f[m] = xr[g];
        }
    }

    // output j (j=0,1) uses f[2j+2 .. 2j+9]
    float a0 = f[2] * WLc(0), d0 = f[2] * WHc(0);
    float a1 = f[4] * WLc(0), d1 = f[4] * WHc(0);
    #pragma unroll
    for (int t = 1; t < 8; ++t) {
        a0 = fmaf(f[2 + t], WLc(t), a0);
        d0 = fmaf(f[2 + t], WHc(t), d0);
        a1 = fmaf(f[4 + t], WLc(t), a1);
        d1 = fmaf(f[4 + t], WHc(t), d1);
    }

    const long long obase = (long long)row * K + k0;
    float* __restrict__ oA = out + obase;
    float* __restrict__ oD = oA + (long long)B * K;   // B*K even -> same parity

    if (K - k0 >= 2) {
        if ((obase & 1) == 0) {
            *reinterpret_cast<float2*>(oA) = make_float2(a0, a1);
            *reinterpret_cast<float2*>(oD) = make_float2(d0, d1);
        } else {
            oA[0] = a0; oA[1] = a1;
            oD[0] = d0; oD[1] = d1;
        }
    } else {
        oA[0] = a0; oD[0] = d0;   // K odd: last output of the row
    }
}

__global__ void copy_tail_kernel(const float* __restrict__ src,
                                 float* __restrict__ dst, int n)
{
    int i = blockIdx.x * blockDim.x + threadIdx.x;
    if (i < n) dst[i] = src[i];
}

extern "C" void kernel_launch(void* const* d_in, const int* in_sizes, int n_in,
                              void* d_out, int out_size, void* d_ws, size_t ws_size,
                              hipStream_t stream) {
    const float* x1 = (const float*)d_in[0];
    // d_in[1] = x2: unused by the reference
    const float* x3 = (const float*)d_in[2];
    float* out = (float*)d_out;

    const int B = in_sizes[2] / 8;        // 512
    const int N = in_sizes[0] / B;        // 65536
    const int K = (N + 7) / 2;            // 32771
    const int outs_per_block = 512;       // 256 threads x 2 outputs
    const int tiles = (K + outs_per_block - 1) / outs_per_block;   // 65

    dwt_db4_kernel<<<B * tiles, 256, 0, stream>>>(x1, out, B, N, K, tiles);

    const int n3 = in_sizes[2];           // 4096
    copy_tail_kernel<<<(n3 + 255) / 256, 256, 0, stream>>>(
        x3, out + 2LL * B * K, n3);
}